// Round 10
// baseline (366.219 us; speedup 1.0000x reference)
//
#include <hip/hip_runtime.h>
#include <stdint.h>

// Block_32521492365607: pre-LN(T-axis) attention block, MI355X gfx950.
// Round 10: (a) GEMM ds_reads software-pipelined one ks-chunk ahead (lgkm
// waits land pre-satisfied; MFMA covers the other chunk's reads) — the m201
// "read a phase ahead" trick r7 missed; (b) attention K/V double-buffered,
// one vmcnt(0)+barrier per chunk, stage(c+1) covered by chunk-c compute
// (was: stage then immediate __syncthreads drain = zero cover).
//
// WS layout (bytes):
//   0: BkT 2MB | 2MB: WvT 2MB | 4MB: WpB 2MB | 6MB: W1B 8MB | 14MB: W2B 8MB
//   22MB: hB 8MB | 30MB: qk 8MB | 38MB: Vt 8MB | 46MB: ctx 8MB
//   (ff1 bf16 [4096,4096] overlays 30..62MB after qk/Vt/ctx are dead)
//   62MB: x2 f32 16MB | 78MB: ln stats. Total ~78.3MB.

#define BDIM 256

typedef __attribute__((ext_vector_type(8))) __bf16 bf16x8;
typedef __attribute__((ext_vector_type(4))) float f32x4;

__device__ __forceinline__ unsigned short f2bf(float f) {
    unsigned u = __float_as_uint(f);
    u += 0x7fff + ((u >> 16) & 1);   // RNE
    return (unsigned short)(u >> 16);
}

__device__ __forceinline__ void gload_lds16(const void* g, void* l) {
    __builtin_amdgcn_global_load_lds(
        (const __attribute__((address_space(1))) void*)g,
        (__attribute__((address_space(3))) void*)l, 16, 0, 0);
}

// ---------------- weight prep ----------------
__global__ void k_cast_bf16(const float* __restrict__ in, unsigned short* __restrict__ out, int n4) {
    int i = blockIdx.x * BDIM + threadIdx.x;
    if (i >= n4) return;
    float4 v = ((const float4*)in)[i];
    ushort4 o;
    o.x = f2bf(v.x); o.y = f2bf(v.y); o.z = f2bf(v.z); o.w = f2bf(v.w);
    ((ushort4*)out)[i] = o;
}

// W[h][c][d] (16,1024,64) -> out[(h*64+d)*1024 + c] bf16, LDS transpose tile.
__global__ void k_headT(const float* __restrict__ W, unsigned short* __restrict__ out) {
    __shared__ float tile[64][65];
    const int tid = threadIdx.x;
    const int c0 = blockIdx.x * 64, h = blockIdx.y;
    const float* src = W + ((long)h << 16) + (long)c0 * 64;
    #pragma unroll
    for (int j = 0; j < 16; ++j) {
        int idx = j * 256 + tid;
        tile[idx >> 6][idx & 63] = src[idx];
    }
    __syncthreads();
    #pragma unroll
    for (int j = 0; j < 16; ++j) {
        int idx = j * 256 + tid;
        int d = idx >> 6, c = idx & 63;
        out[(long)(h * 64 + d) * 1024 + c0 + c] = f2bf(tile[c][d]);
    }
}

// ---------------- LayerNorm over T axis ----------------
__global__ void k_ln_part(const float* __restrict__ x, float* __restrict__ psum, float* __restrict__ psq) {
    int c = blockIdx.x * BDIM + threadIdx.x;
    int tc = blockIdx.y, b = blockIdx.z;
    const float* p = x + ((long)b << 20) + ((long)tc * 128) * 1024 + c;
    float s = 0.f, ss = 0.f;
    for (int t = 0; t < 128; ++t) {
        float v = p[t * 1024];
        s += v; ss += v * v;
    }
    int o = (b * 8 + tc) * 1024 + c;
    psum[o] = s; psq[o] = ss;
}

__global__ void k_ln_fin(const float* __restrict__ psum, const float* __restrict__ psq,
                         float* __restrict__ mean, float* __restrict__ rstd) {
    int i = blockIdx.x * BDIM + threadIdx.x;  // 4096 = B*C
    int b = i >> 10, c = i & 1023;
    float s = 0.f, ss = 0.f;
    for (int j = 0; j < 8; ++j) {
        s  += psum[(b * 8 + j) * 1024 + c];
        ss += psq[(b * 8 + j) * 1024 + c];
    }
    float m = s * (1.0f / 1024.0f);
    float var = (ss - 1024.0f * m * m) * (1.0f / 1023.0f);   // ddof=1
    mean[i] = m;
    rstd[i] = rsqrtf(var + 1e-5f);
}

__global__ void k_ln_apply(const float* __restrict__ x, const float* __restrict__ mean,
                           const float* __restrict__ rstd, const float* __restrict__ g,
                           const float* __restrict__ beta, unsigned short* __restrict__ out) {
    int i = blockIdx.x * BDIM + threadIdx.x;   // 1M, 4 elems each
    int flat = i << 2;
    int b = flat >> 20, c = flat & 1023;
    float4 xv = ((const float4*)x)[i];
    float4 mv = *(const float4*)&mean[(b << 10) + c];
    float4 rv = *(const float4*)&rstd[(b << 10) + c];
    float4 gv = *(const float4*)&g[c];
    float4 bv = *(const float4*)&beta[c];
    ushort4 o;
    o.x = f2bf(gv.x * (xv.x - mv.x) * rv.x + bv.x);
    o.y = f2bf(gv.y * (xv.y - mv.y) * rv.y + bv.y);
    o.z = f2bf(gv.z * (xv.z - mv.z) * rv.z + bv.z);
    o.w = f2bf(gv.w * (xv.w - mv.w) * rv.w + bv.w);
    ((ushort4*)out)[i] = o;
}

// prefill for split-K FF2: out[i] = res[i] + bias[col]
__global__ void k_addbias(const float* __restrict__ res, const float* __restrict__ bias,
                          float* __restrict__ out) {
    int i = blockIdx.x * BDIM + threadIdx.x;   // 1M float4
    int c = (i << 2) & 1023;
    float4 r = ((const float4*)res)[i];
    float4 bv = *(const float4*)&bias[c];
    r.x += bv.x; r.y += bv.y; r.z += bv.z; r.w += bv.w;
    ((float4*)out)[i] = r;
}

// ---------------- 128x128 BT GEMM, BK=64, 2 blocks/CU, ds-pipelined -------
// C[i,j] = sum_k A[i,k]*B[j,k]. Per tile: STAGE(t+1); lgkm(0) [ks0 regs,
// issued LAST iteration -> pre-satisfied]; issue ks1 reads; MFMA(ks0)
// covers them; lgkm(0) [~free]; MFMA(ks1); vmcnt(0)+barrier; read next
// tile's ks0. LDS swizzle: slot s of row r holds k-block s^((r>>1)&7)
// (0-conflict, PMC-verified). 64KB LDS + lb(256,2) -> 2 blocks/CU.
// EPI: 0 = bf16 out; 1 = f32 + bias[col] + res; 2 = bf16 relu(v+bias);
//      3 = f32 atomicAdd (split-K via blockIdx.z, sA/sB = k-offset).
template <int EPI>
__global__ __launch_bounds__(256, 2) void k_gemm_bt(
    const unsigned short* __restrict__ A, const unsigned short* __restrict__ B,
    void* __restrict__ Cv, const float* __restrict__ bias, const float* __restrict__ res,
    int N, int K, int ldA, int ldB, long sA, long sB, long sC)
{
    __shared__ __align__(16) unsigned short As[2][128 * 64];
    __shared__ __align__(16) unsigned short Bs[2][128 * 64];
    const int tid = threadIdx.x;
    const int wv = tid >> 6, l = tid & 63;
    const long bz = blockIdx.z;

    // XCD-bijective swizzle (nwg % 8 == 0 for all our grids)
    const int gx = gridDim.x;
    const int nwg = gx * gridDim.y;
    int lin = blockIdx.y * gx + blockIdx.x;
    lin = (lin & 7) * (nwg >> 3) + (lin >> 3);
    const int m0 = (lin / gx) * 128, n0 = (lin % gx) * 128;

    const int lr = l & 15, lg = l >> 4;

    // staging: wave wv, issue L(0..3): row = wv*32 + L*8 + (l>>3), slot l&7;
    // fetch k-block g = (l&7) ^ ((L*4 + (l>>4)) & 7)  [slot^((row>>1)&7)]
    const int srow = wv * 32 + (l >> 3);
    const unsigned short* pA = A + bz * sA + (long)(m0 + srow) * ldA;
    const unsigned short* pB = B + bz * sB + (long)(n0 + srow) * ldB;

    auto stage = [&](int k0, int d) {
        #pragma unroll
        for (int L = 0; L < 4; ++L) {
            const int g = ((l & 7) ^ ((L * 4 + (l >> 4)) & 7)) * 8;
            gload_lds16(pA + (long)(L * 8) * ldA + k0 + g, &As[d][(wv * 4 + L) * 512]);
            gload_lds16(pB + (long)(L * 8) * ldB + k0 + g, &Bs[d][(wv * 4 + L) * 512]);
        }
    };

    f32x4 acc[4][4] = {};
    const int wm = (wv >> 1) * 64, wn = (wv & 1) * 64;
    const int rsw = (lr >> 1) & 7;
    const int ob0 = ((0 + lg) ^ rsw) * 8;   // ks0 read column block
    const int ob1 = ((4 + lg) ^ rsw) * 8;   // ks1 read column block

    const int nt = K >> 6;
    stage(0, 0);
    asm volatile("s_waitcnt vmcnt(0)" ::: "memory");
    __builtin_amdgcn_s_barrier();
    __builtin_amdgcn_sched_barrier(0);

    // prologue: ks0 reads of tile 0
    bf16x8 afA[4], bfA[4];
    #pragma unroll
    for (int fm = 0; fm < 4; ++fm)
        afA[fm] = *(const bf16x8*)&As[0][(wm + fm * 16 + lr) * 64 + ob0];
    #pragma unroll
    for (int fn = 0; fn < 4; ++fn)
        bfA[fn] = *(const bf16x8*)&Bs[0][(wn + fn * 16 + lr) * 64 + ob0];

    for (int t = 0; t < nt; ++t) {
        const int d = t & 1;
        if (t + 1 < nt) stage((t + 1) << 6, d ^ 1);   // issue before compute
        asm volatile("s_waitcnt lgkmcnt(0)" ::: "memory");   // afA/bfA ready (pre-covered)
        __builtin_amdgcn_sched_barrier(0);
        // issue ks1 reads; MFMA(ks0) below covers their latency
        bf16x8 afB[4], bfB[4];
        #pragma unroll
        for (int fm = 0; fm < 4; ++fm)
            afB[fm] = *(const bf16x8*)&As[d][(wm + fm * 16 + lr) * 64 + ob1];
        #pragma unroll
        for (int fn = 0; fn < 4; ++fn)
            bfB[fn] = *(const bf16x8*)&Bs[d][(wn + fn * 16 + lr) * 64 + ob1];
        __builtin_amdgcn_s_setprio(1);
        #pragma unroll
        for (int fm = 0; fm < 4; ++fm)
            #pragma unroll
            for (int fn = 0; fn < 4; ++fn)
                acc[fm][fn] = __builtin_amdgcn_mfma_f32_16x16x32_bf16(afA[fm], bfA[fn], acc[fm][fn], 0, 0, 0);
        __builtin_amdgcn_s_setprio(0);
        asm volatile("s_waitcnt lgkmcnt(0)" ::: "memory");   // afB/bfB (covered by MFMA above)
        __builtin_amdgcn_sched_barrier(0);
        __builtin_amdgcn_s_setprio(1);
        #pragma unroll
        for (int fm = 0; fm < 4; ++fm)
            #pragma unroll
            for (int fn = 0; fn < 4; ++fn)
                acc[fm][fn] = __builtin_amdgcn_mfma_f32_16x16x32_bf16(afB[fm], bfB[fn], acc[fm][fn], 0, 0, 0);
        __builtin_amdgcn_s_setprio(0);
        __builtin_amdgcn_sched_barrier(0);
        asm volatile("s_waitcnt vmcnt(0)" ::: "memory");   // stage(t+1) landed
        __builtin_amdgcn_s_barrier();                      // reads of buf d done
        __builtin_amdgcn_sched_barrier(0);
        if (t + 1 < nt) {
            // next tile's ks0 reads (buf d^1, just staged); covered by loop top
            #pragma unroll
            for (int fm = 0; fm < 4; ++fm)
                afA[fm] = *(const bf16x8*)&As[d ^ 1][(wm + fm * 16 + lr) * 64 + ob0];
            #pragma unroll
            for (int fn = 0; fn < 4; ++fn)
                bfA[fn] = *(const bf16x8*)&Bs[d ^ 1][(wn + fn * 16 + lr) * 64 + ob0];
        }
    }

    const int cr0 = lg * 4;
    #pragma unroll
    for (int fm = 0; fm < 4; ++fm) {
        #pragma unroll
        for (int r = 0; r < 4; ++r) {
            const int row = m0 + wm + fm * 16 + cr0 + r;
            const long rb = bz * sC + (long)row * N;
            #pragma unroll
            for (int fn = 0; fn < 4; ++fn) {
                const int col = n0 + wn + fn * 16 + lr;
                float v = acc[fm][fn][r];
                if (EPI == 0) {
                    ((unsigned short*)Cv)[rb + col] = f2bf(v);
                } else if (EPI == 1) {
                    ((float*)Cv)[rb + col] = v + bias[col] + res[rb + col];
                } else if (EPI == 2) {
                    v += bias[col];
                    ((unsigned short*)Cv)[rb + col] = f2bf(v > 0.f ? v : 0.f);
                } else {
                    atomicAdd(&((float*)Cv)[rb + col], v);
                }
            }
        }
    }
}

// ---------------- flash attention (causal, q==k tensor) ----------------
// K/V chunks double-buffered; ONE vmcnt(0)+barrier per chunk; stage(c+1)
// issued right after the barrier, covered by chunk-c QK/softmax/PV.
#define CEXP 0.18033688f   // 0.125 * log2(e)
#define PSTRIDE 72

__global__ __launch_bounds__(256, 2) void k_attn(
    const unsigned short* __restrict__ qk, const unsigned short* __restrict__ vt,
    unsigned short* __restrict__ ctx)
{
    __shared__ __align__(16) unsigned short Ks[2][64 * 64];
    __shared__ __align__(16) unsigned short Vs[2][64 * 64];
    __shared__ __align__(16) unsigned short P[4][16 * PSTRIDE];
    const int tid = threadIdx.x;
    const int wave = tid >> 6, lane = tid & 63;
    const int bh = blockIdx.x >> 3, pairIdx = blockIdx.x & 7;
    const int b = bh >> 4, h = bh & 15;
    const int lr = lane & 15, lg = lane >> 4;

    const int swz = (lr & 7) << 4;
    const int cby0 = (lg * 16) ^ swz;
    const int cby1 = (64 + lg * 16) ^ swz;
    const int srow_l = lane >> 3;
    const int scol = ((lane & 7) * 8) ^ (srow_l << 3);   // u16 units

    unsigned short* Pw = P[wave];
    char* KsB = (char*)Ks;
    char* VsB = (char*)Vs;
    const unsigned short* qbase = qk + ((long)b << 20) + h * 64;
    const unsigned short* vb    = vt + ((long)(b * 16 + h) << 16);

    #pragma unroll 1
    for (int phase = 0; phase < 2; ++phase) {
        const int qb = phase ? (15 - pairIdx) : pairIdx;
        const int q0 = qb << 6;
        const int qw = q0 + wave * 16;

        const unsigned short* qrow = qbase + (long)(qw + lr) * 1024 + lg * 8;
        const bf16x8 aq0 = *(const bf16x8*)qrow;
        const bf16x8 aq1 = *(const bf16x8*)(qrow + 32);

        f32x4 acc[4] = {};
        float mrow[4] = {-1e30f, -1e30f, -1e30f, -1e30f};
        float lrow[4] = {0.f, 0.f, 0.f, 0.f};

        __syncthreads();   // buffers free of previous phase's reads
        #pragma unroll
        for (int i = 0; i < 2; ++i) {       // stage chunk 0 -> dbuf 0
            const int row = i * 32 + wave * 8 + srow_l;
            gload_lds16(qbase + (long)row * 1024 + scol, KsB + i * 4096 + wave * 1024);
            gload_lds16(vb + (long)row * 1024 + scol, VsB + i * 4096 + wave * 1024);
        }

        for (int c = 0; c <= qb; ++c) {
            const int dB = (c & 1) << 13;   // byte offset of current dbuf
            asm volatile("s_waitcnt vmcnt(0)" ::: "memory");   // chunk c landed
            __builtin_amdgcn_s_barrier();
            __builtin_amdgcn_sched_barrier(0);
            if (c < qb) {                   // stage chunk c+1, covered by compute
                const int k1 = (c + 1) << 6;
                const int dN = ((c + 1) & 1) << 13;
                #pragma unroll
                for (int i = 0; i < 2; ++i) {
                    const int row = i * 32 + wave * 8 + srow_l;
                    gload_lds16(qbase + (long)(k1 + row) * 1024 + scol, KsB + dN + i * 4096 + wave * 1024);
                    gload_lds16(vb + (long)row * 1024 + k1 + scol, VsB + dN + i * 4096 + wave * 1024);
                }
            }

            f32x4 s[4];
            #pragma unroll
            for (int t = 0; t < 4; ++t) {
                const int r = t * 16 + lr;
                bf16x8 bk0 = *(const bf16x8*)(KsB + dB + r * 128 + cby0);
                bf16x8 bk1 = *(const bf16x8*)(KsB + dB + r * 128 + cby1);
                f32x4 z = {};
                z = __builtin_amdgcn_mfma_f32_16x16x32_bf16(aq0, bk0, z, 0, 0, 0);
                s[t] = __builtin_amdgcn_mfma_f32_16x16x32_bf16(aq1, bk1, z, 0, 0, 0);
            }
            if (c == qb) {
                #pragma unroll
                for (int t = 0; t < 4; ++t) {
                    const int col = t * 16 + lr;
                    #pragma unroll
                    for (int r = 0; r < 4; ++r)
                        if (col > wave * 16 + lg * 4 + r) s[t][r] = -1e30f;
                }
            }
            float fac[4];
            #pragma unroll
            for (int r = 0; r < 4; ++r) {
                float v = fmaxf(fmaxf(s[0][r], s[1][r]), fmaxf(s[2][r], s[3][r]));
                v = fmaxf(v, __shfl_xor(v, 1));
                v = fmaxf(v, __shfl_xor(v, 2));
                v = fmaxf(v, __shfl_xor(v, 4));
                v = fmaxf(v, __shfl_xor(v, 8));
                float mn = fmaxf(mrow[r], v);
                fac[r] = exp2f((mrow[r] - mn) * CEXP);
                mrow[r] = mn;
            }
            float psum[4] = {0.f, 0.f, 0.f, 0.f};
            #pragma unroll
            for (int t = 0; t < 4; ++t) {
                #pragma unroll
                for (int r = 0; r < 4; ++r) {
                    float p = exp2f((s[t][r] - mrow[r]) * CEXP);
                    psum[r] += p;
                    Pw[(lg * 4 + r) * PSTRIDE + t * 16 + lr] = f2bf(p);
                }
            }
            #pragma unroll
            for (int r = 0; r < 4; ++r) {
                float v = psum[r];
                v += __shfl_xor(v, 1); v += __shfl_xor(v, 2);
                v += __shfl_xor(v, 4); v += __shfl_xor(v, 8);
                lrow[r] = lrow[r] * fac[r] + v;
            }
            #pragma unroll
            for (int ni = 0; ni < 4; ++ni)
                #pragma unroll
                for (int r = 0; r < 4; ++r)
                    acc[ni][r] *= fac[r];
            const bf16x8 pa0 = *(const bf16x8*)&Pw[lr * PSTRIDE + lg * 8];
            const bf16x8 pa1 = *(const bf16x8*)&Pw[lr * PSTRIDE + 32 + lg * 8];
            #pragma unroll
            for (int ni = 0; ni < 4; ++ni) {
                const int vr = ni * 16 + lr;
                bf16x8 bv0 = *(const bf16x8*)(VsB + dB + vr * 128 + cby0);
                bf16x8 bv1 = *(const bf16x8*)(VsB + dB + vr * 128 + cby1);
                acc[ni] = __builtin_amdgcn_mfma_f32_16x16x32_bf16(pa0, bv0, acc[ni], 0, 0, 0);
                acc[ni] = __builtin_amdgcn_mfma_f32_16x16x32_bf16(pa1, bv1, acc[ni], 0, 0, 0);
            }
        }

        unsigned short* crow = ctx + ((long)(b * 1024 + qw)) * 1024 + h * 64;
        #pragma unroll
        for (int r = 0; r < 4; ++r) {
            const float inv = 1.0f / lrow[r];
            #pragma unroll
            for (int ni = 0; ni < 4; ++ni)
                crow[(long)(lg * 4 + r) * 1024 + ni * 16 + lr] = f2bf(acc[ni][r] * inv);
        }
    }
}

// ---------------- launcher ----------------
extern "C" void kernel_launch(void* const* d_in, const int* in_sizes, int n_in,
                              void* d_out, int out_size, void* d_ws, size_t ws_size,
                              hipStream_t stream)
{
    const float* x   = (const float*)d_in[0];
    const float* Wk  = (const float*)d_in[1];
    const float* Wv  = (const float*)d_in[2];
    const float* Wp  = (const float*)d_in[3];
    const float* bp  = (const float*)d_in[4];
    const float* W1  = (const float*)d_in[5];
    const float* b1  = (const float*)d_in[6];
    const float* W2  = (const float*)d_in[7];
    const float* b2  = (const float*)d_in[8];
    const float* g1  = (const float*)d_in[9];
    const float* be1 = (const float*)d_in[10];
    const float* g2  = (const float*)d_in[11];
    const float* be2 = (const float*)d_in[12];
    float* out = (float*)d_out;

    char* ws = (char*)d_ws;
    const long MB = 1024 * 1024;
    unsigned short* BkT = (unsigned short*)(ws);
    unsigned short* WvT = (unsigned short*)(ws + 2 * MB);
    unsigned short* WpB = (unsigned short*)(ws + 4 * MB);
    unsigned short* W1B = (unsigned short*)(ws + 6 * MB);
    unsigned short* W2B = (unsigned short*)(ws + 14 * MB);
    unsigned short* hB  = (unsigned short*)(ws + 22 * MB);
    unsigned short* qkB = (unsigned short*)(ws + 30 * MB);
    unsigned short* VtB = (unsigned short*)(ws + 38 * MB);
    unsigned short* ctx = (unsigned short*)(ws + 46 * MB);
    unsigned short* ff1 = (unsigned short*)(ws + 30 * MB);  // overlays qk/Vt/ctx
    float* x2   = (float*)(ws + 62 * MB);
    float* psum = (float*)(ws + 78 * MB);
    float* psq  = (float*)(ws + 78 * MB + 128 * 1024);
    float* mean = (float*)(ws + 78 * MB + 256 * 1024);
    float* rstd = (float*)(ws + 78 * MB + 272 * 1024);

    // weight prep
    k_cast_bf16<<<1024, BDIM, 0, stream>>>(Wp, WpB, 262144);
    k_cast_bf16<<<4096, BDIM, 0, stream>>>(W1, W1B, 1048576);
    k_cast_bf16<<<4096, BDIM, 0, stream>>>(W2, W2B, 1048576);
    k_headT<<<dim3(16, 16), BDIM, 0, stream>>>(Wk, BkT);
    k_headT<<<dim3(16, 16), BDIM, 0, stream>>>(Wv, WvT);

    // LN1 (over T axis)
    k_ln_part<<<dim3(4, 8, 4), BDIM, 0, stream>>>(x, psum, psq);
    k_ln_fin<<<16, BDIM, 0, stream>>>(psum, psq, mean, rstd);
    k_ln_apply<<<4096, BDIM, 0, stream>>>(x, mean, rstd, g1, be1, hB);

    // projections
    k_gemm_bt<0><<<dim3(8, 32, 1), BDIM, 0, stream>>>(hB, BkT, qkB, nullptr, nullptr, 1024, 1024, 1024, 1024, 0, 0, 0);
    k_gemm_bt<0><<<dim3(8, 8, 4), BDIM, 0, stream>>>(WvT, hB, VtB, nullptr, nullptr, 1024, 1024, 1024, 1024, 0, MB, MB);

    // flash attention -> ctx bf16 [4096, 1024]
    k_attn<<<512, BDIM, 0, stream>>>(qkB, VtB, ctx);

    // out-proj + bias + residual -> x2 f32
    k_gemm_bt<1><<<dim3(8, 32, 1), BDIM, 0, stream>>>(ctx, WpB, x2, bp, x, 1024, 1024, 1024, 1024, 0, 0, 0);

    // LN2
    k_ln_part<<<dim3(4, 8, 4), BDIM, 0, stream>>>(x2, psum, psq);
    k_ln_fin<<<16, BDIM, 0, stream>>>(psum, psq, mean, rstd);
    k_ln_apply<<<4096, BDIM, 0, stream>>>(x2, mean, rstd, g2, be2, hB);

    // FF1: ff1 = relu(h2 @ W1^T + b1) bf16, grid 1024 -> 2 blocks/CU resident
    k_gemm_bt<2><<<dim3(32, 32, 1), BDIM, 0, stream>>>(hB, W1B, ff1, b1, nullptr, 4096, 1024, 1024, 1024, 0, 0, 0);

    // FF2 split-K=2: out = x2 + b2 (prefill), then out += ff1 @ W2^T (atomic)
    k_addbias<<<4096, BDIM, 0, stream>>>(x2, b2, out);
    k_gemm_bt<3><<<dim3(8, 32, 2), BDIM, 0, stream>>>(ff1, W2B, out, nullptr, nullptr, 1024, 2048, 4096, 4096, 2048, 2048, 0);
}